// Round 2
// baseline (10713.103 us; speedup 1.0000x reference)
//
#include <hip/hip_runtime.h>
#include <math.h>

#define DEV __device__ __forceinline__

DEV float sp_(float x){ float m=fmaxf(x,0.f); return m + log1pf(expf(-fabsf(x))); }
DEV float sig_(float x){ return 1.f/(1.f+expf(-x)); }
DEV float kld_(float m1,float s1,float m2,float s2){
  float d=m1-m2;
  return 2.f*(logf(s2)-logf(s1)) + (s1*s1+d*d)/(s2*s2) - 1.f;
}

DEV float blockReduceSum(float v){
  __shared__ float sh[8];
  #pragma unroll
  for(int o=32;o>0;o>>=1) v += __shfl_down(v,o,64);
  int lane = threadIdx.x & 63, wid = threadIdx.x >> 6;
  if(lane==0) sh[wid]=v;
  __syncthreads();
  float r = 0.f;
  if(threadIdx.x < (int)(blockDim.x>>6)) r = sh[threadIdx.x];
  if(wid==0){
    #pragma unroll
    for(int o=4;o>0;o>>=1) r += __shfl_down(r,o,64);
  }
  return r;  // valid in thread 0
}

// Generic fp32 GEMM: C = act( A@B + bias + Cadd_broadcast ), A may be a
// "virtual concat" [A1 | A2] along K (saves materializing concats).
// B row-major [K][N]. M must be a multiple of BM_. N arbitrary (guarded).
template<int BM_>
__global__ __launch_bounds__(256)
void gemm_k(const float* __restrict__ A1, int lda1, int K1,
            const float* __restrict__ A2, int lda2, int K2,
            const float* __restrict__ Bm, int ldb,
            const float* __restrict__ bias,
            const float* __restrict__ Cadd, int rowmask, int ldcadd,
            float* __restrict__ Cm, int ldc, int M, int N, int relu)
{
  constexpr int BN = 64, BK = 16;
  constexpr int TM = BM_/16;              // 4 (BM=64) or 2 (BM=32)
  constexpr int CH = (BM_*BK)/256;        // floats per thread for A tile: 4 or 2
  constexpr int TPR = BK/CH;              // threads per A row: 4 or 8
  __shared__ float As[BK][BM_+1];         // +1 pad: conflict-free transpose-store
  __shared__ float Bs[BK][BN];
  int tid = threadIdx.x;
  int row0 = blockIdx.y * BM_;
  int col0 = blockIdx.x * BN;
  int tx = tid & 15, ty = tid >> 4;
  int arow = tid / TPR;
  int ak = (tid % TPR) * CH;
  int brow = tid >> 4;
  int bn = (tid & 15) * 4;
  float acc[TM][4];
  #pragma unroll
  for(int i=0;i<TM;i++){
    #pragma unroll
    for(int j=0;j<4;j++) acc[i][j]=0.f;
  }
  bool nfull = (col0 + BN <= N);
  int Kt = K1 + K2;
  for(int k0=0;k0<Kt;k0+=BK){
    int kg = k0 + ak;   // CH-chunks never straddle K1 (K1 % CH == 0 in all uses)
    const float* ap = (kg < K1) ? (A1 + (size_t)(row0+arow)*lda1 + kg)
                                : (A2 + (size_t)(row0+arow)*lda2 + (kg-K1));
    if constexpr (CH==4){
      float4 v = *(const float4*)ap;
      As[ak+0][arow]=v.x; As[ak+1][arow]=v.y; As[ak+2][arow]=v.z; As[ak+3][arow]=v.w;
    } else {
      float2 v = *(const float2*)ap;
      As[ak+0][arow]=v.x; As[ak+1][arow]=v.y;
    }
    int kb = k0 + brow;
    if(nfull){
      float4 v = *(const float4*)(Bm + (size_t)kb*ldb + col0 + bn);
      *(float4*)&Bs[brow][bn] = v;
    } else {
      #pragma unroll
      for(int j=0;j<4;j++){
        int c = col0+bn+j;
        Bs[brow][bn+j] = (c<N) ? Bm[(size_t)kb*ldb + c] : 0.f;
      }
    }
    __syncthreads();
    #pragma unroll
    for(int kk=0;kk<BK;kk++){
      float a[TM], b[4];
      #pragma unroll
      for(int i=0;i<TM;i++) a[i]=As[kk][ty*TM+i];
      #pragma unroll
      for(int j=0;j<4;j++) b[j]=Bs[kk][tx*4+j];
      #pragma unroll
      for(int i=0;i<TM;i++){
        #pragma unroll
        for(int j=0;j<4;j++) acc[i][j] = fmaf(a[i], b[j], acc[i][j]);
      }
    }
    __syncthreads();
  }
  #pragma unroll
  for(int i=0;i<TM;i++){
    int r = row0 + ty*TM + i;
    #pragma unroll
    for(int j=0;j<4;j++){
      int c = col0 + tx*4 + j;
      if(c >= N) continue;
      float v = acc[i][j];
      if(Cadd) v += Cadd[(size_t)(r & rowmask)*ldcadd + c];
      if(bias) v += bias[c];
      if(relu) v = fmaxf(v, 0.f);
      Cm[(size_t)r*ldc + c] = v;
    }
  }
}

// zero accumulators (5 output scalars + sym/symf arrays)
__global__ void k_init(float* S, float* sym){
  int t=threadIdx.x; if(t<5) S[t]=0.f; if(t<48) sym[t]=0.f;
}

__global__ void k_copy(const float* __restrict__ s, float* __restrict__ d, int n){
  int i=blockIdx.x*blockDim.x+threadIdx.x; if(i<n) d[i]=s[i];
}

// fused: kacc += 0.5*sum(kld_e(enc,sp(enc),pri,sp(pri)));  zt = eps*sp(enc)+enc
__global__ void k_kldzt(const float* __restrict__ enc, const float* __restrict__ pri,
                        const float* __restrict__ eps, float* __restrict__ zt,
                        float* kacc, int n){
  float loc=0.f;
  for(int i=blockIdx.x*blockDim.x+threadIdx.x; i<n; i+=gridDim.x*blockDim.x){
    float m1=enc[i], m2=pri[i];
    float s1=sp_(m1), s2=sp_(m2);
    loc += kld_(m1,s1,m2,s2);
    zt[i] = fmaf(eps[i], s1, m1);
  }
  loc = blockReduceSum(loc);
  if(threadIdx.x==0) atomicAdd(kacc, 0.5f*loc);
}

// out[i] = mean[i % per] + eps[i]*sp(mean[i % per])   (reparam w/ broadcast)
__global__ void k_expand(const float* __restrict__ mean, const float* __restrict__ eps,
                         float* __restrict__ out, int per, int total){
  int i = blockIdx.x*blockDim.x+threadIdx.x;
  if(i<total){
    float m = mean[i % per];
    out[i] = fmaf(eps[i], sp_(m), m);
  }
}

// sym[a] += 0.5*sum( (s1^2+d^2)/s2^2 + (s2^2+d^2)/s1^2 - 2 )  (logs cancel in the
// symmetric KLD pair)
__global__ void k_sym(const float* __restrict__ om, const float* __restrict__ en,
                      float* sym, int n){
  int a = blockIdx.y;
  const float* e = en + (size_t)a*n;
  float loc=0.f;
  for(int i=blockIdx.x*blockDim.x+threadIdx.x; i<n; i+=gridDim.x*blockDim.x){
    float m1=om[i], m2=e[i];
    float s1=sp_(m1), s2=sp_(m2);
    float d=m1-m2, d2=d*d, q1=s1*s1, q2=s2*s2;
    loc += (q1+d2)/q2 + (q2+d2)/q1 - 2.f;
  }
  loc = blockReduceSum(loc);
  if(threadIdx.x==0) atomicAdd(&sym[a], 0.5f*loc);
}

__global__ void k_argmin(const float* sym, int n, int* jsel, float* dis, int add){
  if(threadIdx.x==0 && blockIdx.x==0){
    float m=sym[0]; int j=0;
    for(int a=1;a<n;a++) if(sym[a]<m){m=sym[a];j=a;}
    *jsel=j;
    if(add) *dis += m; else *dis = m;
  }
}

__global__ void k_kldsel(const float* __restrict__ en, const float* __restrict__ pn,
                         const int* jsel, int per, float* out){
  size_t base = (size_t)(*jsel)*per;
  float loc=0.f;
  for(int i=blockIdx.x*blockDim.x+threadIdx.x; i<per; i+=gridDim.x*blockDim.x){
    float m1=en[base+i], m2=pn[base+i];
    loc += kld_(m1, sp_(m1), m2, sp_(m2));
  }
  loc=blockReduceSum(loc);
  if(threadIdx.x==0) atomicAdd(out, 0.5f*loc);
}

__global__ void k_gather(const float* __restrict__ src, const int* jsel,
                         float* __restrict__ dst, int per){
  int i=blockIdx.x*blockDim.x+threadIdx.x;
  if(i<per) dst[i]=src[(size_t)(*jsel)*per+i];
}

// PyTorch GRU gate math, h updated in place
__global__ void k_gru(const float* __restrict__ gi, const float* __restrict__ gh,
                      float* __restrict__ h, int B_, int H_){
  int i=blockIdx.x*blockDim.x+threadIdx.x;
  if(i<B_*H_){
    int b=i/H_, c=i%H_;
    const float* gib=gi+(size_t)b*3*H_;
    const float* ghb=gh+(size_t)b*3*H_;
    float r=sig_(gib[c]+ghb[c]);
    float u=sig_(gib[H_+c]+ghb[H_+c]);
    float nn=tanhf(fmaf(r, ghb[2*H_+c], gib[2*H_+c]));
    h[i]=(1.f-u)*nn + u*h[i];
  }
}

extern "C" void kernel_launch(void* const* d_in, const int* in_sizes, int n_in,
                              void* d_out, int out_size, void* d_ws, size_t ws_size,
                              hipStream_t stream)
{
  const int T=32, B=512, F=512, H=512, Z=256, G=3, A=10, C=1000;
  const float* feat   = (const float*)d_in[0];
  const float* h0     = (const float*)d_in[1];
  const float* eps_z  = (const float*)d_in[2];
  const float* eps_g  = (const float*)d_in[3];
  const float* eps_n  = (const float*)d_in[4];
  const float* eps_f  = (const float*)d_in[5];
  const float* Wpx=(const float*)d_in[6],  *bpx=(const float*)d_in[7];
  const float* Wenc1=(const float*)d_in[8],*benc1=(const float*)d_in[9];
  const float* Wenc2=(const float*)d_in[10],*benc2=(const float*)d_in[11];
  const float* Wpr1=(const float*)d_in[12],*bpr1=(const float*)d_in[13];
  const float* Wpr2=(const float*)d_in[14],*bpr2=(const float*)d_in[15];
  const float* Wpz=(const float*)d_in[16], *bpz=(const float*)d_in[17];
  const float* Wih1=(const float*)d_in[18],*Whh1=(const float*)d_in[19];
  const float* bih1=(const float*)d_in[20],*bhh1=(const float*)d_in[21];
  const float* Wzn=(const float*)d_in[22], *bzn=(const float*)d_in[23];
  const float* Wprn1=(const float*)d_in[24],*bprn1=(const float*)d_in[25];
  const float* Wprn2=(const float*)d_in[26],*bprn2=(const float*)d_in[27];
  const float* Wga=(const float*)d_in[28], *bga=(const float*)d_in[29];
  const float* Woa1=(const float*)d_in[30],*boa1=(const float*)d_in[31];
  const float* Woa2=(const float*)d_in[32],*boa2=(const float*)d_in[33];
  const float* Wna1=(const float*)d_in[34],*bna1=(const float*)d_in[35];
  const float* Wna2=(const float*)d_in[36],*bna2=(const float*)d_in[37];
  const float* Wen=(const float*)d_in[38], *ben=(const float*)d_in[39];
  const float* Wact=(const float*)d_in[40],*bact=(const float*)d_in[41];
  const float* Wih2=(const float*)d_in[42],*Whh2=(const float*)d_in[43];
  const float* bih2=(const float*)d_in[44],*bhh2=(const float*)d_in[45];
  const float* Wcc=(const float*)d_in[46], *bcc=(const float*)d_in[47];
  const float* Wnc=(const float*)d_in[48], *bnc=(const float*)d_in[49];

  float* ws = (float*)d_ws;
  size_t off = 0;
  auto alloc = [&](size_t n){ float* p = ws + off; off += n; return p; };
  // common buffers (~53 MB)
  float* Hb  = alloc((size_t)B*H);      // h / ha (in-place GRU)
  float* E1  = alloc((size_t)B*H);      // e1 / zn
  float* P1  = alloc((size_t)B*H);      // hidden of all 2-layer MLPs
  float* ZP  = alloc((size_t)B*H);
  float* NM  = alloc((size_t)B*H);      // next_mean / fmean
  float* OA  = alloc((size_t)B*H);      // obs_act (persists)
  float* PAb = alloc((size_t)B*H);
  float* CAb = alloc((size_t)B*H);
  float* GI  = alloc((size_t)B*3*H);
  float* GH  = alloc((size_t)B*3*H);
  float* ENC = alloc((size_t)B*Z);
  float* PRI = alloc((size_t)B*Z);
  float* ZT  = alloc((size_t)B*Z);      // zt / obs_goal
  float* OM  = alloc((size_t)B*Z);      // obs_mean (persists)
  float* PNH = alloc((size_t)B*Z);      // pn_h / pn
  float* OAZ = alloc((size_t)B*Z);      // obs_act_z / pre_z
  float* BASE= alloc((size_t)B*Z);
  float* NACT= alloc((size_t)A*B*H);    // next_act / fact
  float* PMID= alloc((size_t)A*B*H);
  float* PNX = alloc((size_t)A*B*Z);    // pnext / pf
  float* ENCN= alloc((size_t)A*B*Z);    // enc_next / encf
  float* BUFA= alloc((size_t)B*H);
  float* BUFB= alloc((size_t)B*H);
  float* BUFC= alloc((size_t)B*H);
  float* SYM = alloc(16);               // sym[10]
  float* SYMF0 = alloc(16);
  float* SYMF1 = alloc(16);
  int*   JSEL = (int*)alloc(16);
  size_t common = off;
  // phix: keep the full [T,B,H] if the workspace allows (one big GEMM, best
  // occupancy op in the whole chain); otherwise compute xp per step.
  bool bigphix = (common + (size_t)T*B*H) * 4 <= ws_size;
  float* PHIX = nullptr; float* XP = nullptr;
  if (bigphix) PHIX = alloc((size_t)T*B*H);
  else         XP   = alloc((size_t)B*H);

  float* outCur = (float*)d_out;
  float* outFut = outCur + (size_t)B*C;
  float* S      = outCur + (size_t)B*C*4;   // 5 scalar slots

  auto gemm = [&](const float* A1,int lda1,int K1,
                  const float* A2,int lda2,int K2,
                  const float* Bw,int ldb, const float* bias,
                  const float* Cadd,int rowmask,int ldcadd,
                  float* Cm,int ldc,int M,int N,int relu){
    if(M > 512){
      dim3 g((N+63)/64, M/64);
      gemm_k<64><<<g,256,0,stream>>>(A1,lda1,K1, A2?A2:A1,lda2,K2, Bw,ldb,bias,
                                     Cadd,rowmask,ldcadd, Cm,ldc,M,N,relu);
    } else {
      dim3 g((N+63)/64, M/32);
      gemm_k<32><<<g,256,0,stream>>>(A1,lda1,K1, A2?A2:A1,lda2,K2, Bw,ldb,bias,
                                     Cadd,rowmask,ldcadd, Cm,ldc,M,N,relu);
    }
  };
  auto ew = [&](int n){ return dim3((n+255)/256); };

  k_init<<<1,64,0,stream>>>(S, SYM);
  k_copy<<<ew(B*H),256,0,stream>>>(h0, Hb, B*H);
  if(bigphix)
    gemm(feat,F,F, 0,0,0, Wpx,H,bpx, 0,0,0, PHIX,H, T*B,H, 1);

  // ---- scan over T steps ----
  for(int t=0;t<T;t++){
    const float* xp;
    if(bigphix) xp = PHIX + (size_t)t*B*H;
    else { gemm(feat+(size_t)t*B*F,F,F, 0,0,0, Wpx,H,bpx, 0,0,0, XP,H, B,H, 1); xp = XP; }
    const float* epz = eps_z + (size_t)t*B*Z;
    gemm(Hb,H,H, xp,H,H, Wenc1,H,benc1, 0,0,0, E1,H, B,H, 1);        // relu(concat(h,xp)@Wenc1)
    gemm(E1,H,H, 0,0,0, Wenc2,Z,benc2, 0,0,0, ENC,Z, B,Z, 0);        // enc
    gemm(Hb,H,H, 0,0,0, Wpr1,H,bpr1, 0,0,0, P1,H, B,H, 1);
    gemm(P1,H,H, 0,0,0, Wpr2,Z,bpr2, 0,0,0, PRI,Z, B,Z, 0);         // pri
    k_kldzt<<<128,256,0,stream>>>(ENC,PRI,epz,ZT,&S[0],B*Z);
    gemm(ZT,Z,Z, 0,0,0, Wpz,H,bpz, 0,0,0, ZP,H, B,H, 1);            // relu(zt@Wpz)
    gemm(xp,H,H, ZP,H,H, Wih1,3*H,bih1, 0,0,0, GI,3*H, B,3*H, 0);   // gi
    gemm(Hb,H,H, 0,0,0, Whh1,3*H,bhh1, 0,0,0, GH,3*H, B,3*H, 0);    // gh
    k_gru<<<ew(B*H),256,0,stream>>>(GI,GH,Hb,B,H);
  }

  // ---- phase 3: only g = G-1 reaches any output ----
  gemm(Hb,H,H, 0,0,0, Wpr1,H,bpr1, 0,0,0, P1,H, B,H, 1);
  gemm(P1,H,H, 0,0,0, Wpr2,Z,bpr2, 0,0,0, OM,Z, B,Z, 0);            // obs_mean
  gemm(Hb,H,H, 0,0,0, Wprn1,H,bprn1, 0,0,0, P1,H, B,H, 1);
  gemm(P1,H,H, 0,0,0, Wprn2,Z,bprn2, 0,0,0, PNH,Z, B,Z, 0);         // pn_h
  k_expand<<<ew(B*Z),256,0,stream>>>(OM, eps_g+(size_t)(G-1)*B*Z, ZT, B*Z, B*Z); // obs_goal
  gemm(ZT,Z,Z, 0,0,0, Wzn,H,bzn, 0,0,0, E1,H, B,H, 1);              // zn
  gemm(E1,H,H, PNH,Z,Z, Wga,H,bga, 0,0,0, OA,H, B,H, 1);            // obs_act
  gemm(PNH,Z,Z, OA,H,H, Wga,H,bga, 0,0,0, NM,H, B,H, 1);            // next_mean
  k_expand<<<ew(A*B*H),256,0,stream>>>(NM, eps_n+(size_t)(G-1)*A*B*H, NACT, B*H, A*B*H);
  gemm(NACT,H,H, 0,0,0, Wna1,H,bna1, 0,0,0, PMID,H, A*B,H, 1);
  gemm(PMID,H,H, 0,0,0, Wna2,Z,bna2, 0,0,0, PNX,Z, A*B,Z, 0);       // pnext
  gemm(OA,H,H, 0,0,0, Woa1,H,boa1, 0,0,0, P1,H, B,H, 1);
  gemm(P1,H,H, 0,0,0, Woa2,Z,boa2, 0,0,0, OAZ,Z, B,Z, 0);           // obs_act_z
  gemm(OAZ,Z,Z, 0,0,0, Wen+(size_t)Z*Z,Z, ben, 0,0,0, BASE,Z, B,Z, 0);
  gemm(PNX,Z,Z, 0,0,0, Wen,Z, 0, BASE,B-1,Z, ENCN,Z, A*B,Z, 1);     // enc_next
  k_sym<<<dim3(32,A),256,0,stream>>>(OM, ENCN, SYM, B*Z);
  k_argmin<<<1,64,0,stream>>>(SYM, A, &JSEL[0], &S[2], 0);          // lat_goal_dis
  k_kldsel<<<128,256,0,stream>>>(ENCN, PNX, &JSEL[0], B*Z, &S[1]);  // kld_next
  k_gather<<<ew(B*H),256,0,stream>>>(NACT, &JSEL[0], BUFA, B*H);    // next_act_final

  // ---- phase 4: 2 future steps ----
  const float* pre = OA; const float* cur = BUFA;
  float* futbuf[2] = {BUFB, BUFC};
  for(int i=0;i<2;i++){
    gemm(pre,H,H, 0,0,0, Wact,H,bact, 0,0,0, PAb,H, B,H, 1);
    gemm(cur,H,H, 0,0,0, Wact,H,bact, 0,0,0, CAb,H, B,H, 1);
    gemm(PAb,H,H, CAb,H,H, Wih2,3*H,bih2, 0,0,0, GI,3*H, B,3*H, 0);
    gemm(Hb,H,H, 0,0,0, Whh2,3*H,bhh2, 0,0,0, GH,3*H, B,3*H, 0);
    k_gru<<<ew(B*H),256,0,stream>>>(GI,GH,Hb,B,H);
    pre = cur;
    gemm(Hb,H,H, 0,0,0, Wprn1,H,bprn1, 0,0,0, P1,H, B,H, 1);
    gemm(P1,H,H, 0,0,0, Wprn2,Z,bprn2, 0,0,0, PNH,Z, B,Z, 0);
    gemm(PNH,Z,Z, pre,H,H, Wga,H,bga, 0,0,0, NM,H, B,H, 1);         // fmean
    k_expand<<<ew(A*B*H),256,0,stream>>>(NM, eps_f+(size_t)i*A*B*H, NACT, B*H, A*B*H);
    gemm(NACT,H,H, 0,0,0, Wna1,H,bna1, 0,0,0, PMID,H, A*B,H, 1);
    gemm(PMID,H,H, 0,0,0, Wna2,Z,bna2, 0,0,0, PNX,Z, A*B,Z, 0);     // pf
    gemm(pre,H,H, 0,0,0, Wna1,H,bna1, 0,0,0, P1,H, B,H, 1);
    gemm(P1,H,H, 0,0,0, Wna2,Z,bna2, 0,0,0, OAZ,Z, B,Z, 0);         // pre_z
    gemm(OAZ,Z,Z, 0,0,0, Wen+(size_t)Z*Z,Z, ben, 0,0,0, BASE,Z, B,Z, 0);
    gemm(PNX,Z,Z, 0,0,0, Wen,Z, 0, BASE,B-1,Z, ENCN,Z, A*B,Z, 1);   // encf
    float* symf = (i==0)?SYMF0:SYMF1;
    k_sym<<<dim3(32,A),256,0,stream>>>(OM, ENCN, symf, B*Z);
    k_argmin<<<1,64,0,stream>>>(symf, A, &JSEL[1+i], &S[4], 1);     // future_dis +=
    k_kldsel<<<128,256,0,stream>>>(ENCN, PNX, &JSEL[1+i], B*Z, &S[3]); // kld_future +=
    k_gather<<<ew(B*H),256,0,stream>>>(NACT, &JSEL[1+i], futbuf[i], B*H);
    cur = futbuf[i];
  }

  // ---- outputs ----
  gemm(OA,H,H, 0,0,0, Wcc,C,bcc, 0,0,0, outCur,C, B,C, 0);
  gemm(BUFA,H,H, 0,0,0, Wnc,C,bnc, 0,0,0, outFut,C, B,C, 0);
  gemm(BUFB,H,H, 0,0,0, Wnc,C,bnc, 0,0,0, outFut+(size_t)B*C,C, B,C, 0);
  gemm(BUFC,H,H, 0,0,0, Wnc,C,bnc, 0,0,0, outFut+(size_t)2*B*C,C, B,C, 0);
}

// Round 3
// 7852.054 us; speedup vs baseline: 1.3644x; 1.3644x over previous
//
#include <hip/hip_runtime.h>
#include <math.h>

#define DEV __device__ __forceinline__

DEV float sp_(float x){ float m=fmaxf(x,0.f); return m + log1pf(expf(-fabsf(x))); }
DEV float sig_(float x){ return 1.f/(1.f+expf(-x)); }
DEV float kld_(float m1,float s1,float m2,float s2){
  float d=m1-m2;
  return 2.f*(logf(s2)-logf(s1)) + (s1*s1+d*d)/(s2*s2) - 1.f;
}

DEV float blockReduceSum(float v){
  __shared__ float sh[8];
  #pragma unroll
  for(int o=32;o>0;o>>=1) v += __shfl_down(v,o,64);
  int lane = threadIdx.x & 63, wid = threadIdx.x >> 6;
  if(lane==0) sh[wid]=v;
  __syncthreads();
  float r = 0.f;
  if(threadIdx.x < (int)(blockDim.x>>6)) r = sh[threadIdx.x];
  if(wid==0){
    #pragma unroll
    for(int o=4;o>0;o>>=1) r += __shfl_down(r,o,64);
  }
  return r;  // valid in thread 0
}

// fp32 GEMM, C = epilogue(A@B): A is virtual K-concat [A1|A2], B row-major
// [K][N]. 256 threads, BK=32, BN=64, per-thread tile TM x 4 (float4 acc).
// relu applied to columns c < relu_cut. N%4==0 required (true for all uses).
template<int BM>
__global__ __launch_bounds__(256)
void gemm_k(const float* __restrict__ A1, int lda1, int K1,
            const float* __restrict__ A2, int lda2, int K2,
            const float* __restrict__ Bm, int ldb,
            const float* __restrict__ bias,
            const float* __restrict__ Cadd, int rowmask, int ldcadd,
            float* __restrict__ Cm, int ldc, int N, int relu_cut)
{
  constexpr int BN = 64, BK = 32;
  constexpr int TM = BM/16;                 // 4 / 2 / 1
  constexpr int PAD = (BM>=32) ? 4 : 1;     // keep 16B alignment of As rows for BM>=32
  __shared__ float As[BK][BM+PAD];
  __shared__ float Bs[BK][BN];
  const int tid = threadIdx.x;
  const int row0 = blockIdx.y * BM;
  const int col0 = blockIdx.x * BN;
  const int tx = tid & 15, ty = tid >> 4;
  float4 acc[TM];
  #pragma unroll
  for(int i=0;i<TM;i++) acc[i] = make_float4(0.f,0.f,0.f,0.f);
  const int Kt = K1 + K2;
  for(int k0=0; k0<Kt; k0+=BK){
    // ---- stage A (transposed to As[k][m]) ----
    if constexpr (BM>=32){
      #pragma unroll
      for(int j=0;j<BM/32;j++){
        int ci = tid + j*256;
        int r  = ci >> 3;        // 8 float4-chunks per row of 32 k
        int kq = ci & 7;
        int kg = k0 + kq*4;      // chunks never straddle K1 (K1%4==0 in all uses)
        const float* ap = (kg < K1) ? (A1 + (size_t)(row0+r)*lda1 + kg)
                                    : (A2 + (size_t)(row0+r)*lda2 + (kg-K1));
        float4 v = *(const float4*)ap;
        As[kq*4+0][r]=v.x; As[kq*4+1][r]=v.y; As[kq*4+2][r]=v.z; As[kq*4+3][r]=v.w;
      }
    } else {
      int r  = tid >> 4;         // 16 rows
      int kq = tid & 15;         // 16 float2-chunks per row
      int kg = k0 + kq*2;
      const float* ap = (kg < K1) ? (A1 + (size_t)(row0+r)*lda1 + kg)
                                  : (A2 + (size_t)(row0+r)*lda2 + (kg-K1));
      float2 v = *(const float2*)ap;
      As[kq*2+0][r]=v.x; As[kq*2+1][r]=v.y;
    }
    // ---- stage B ----
    #pragma unroll
    for(int j=0;j<2;j++){
      int ci = tid + j*256;
      int r = ci >> 4, c4 = ci & 15;
      int c = col0 + c4*4;
      float4 v = make_float4(0.f,0.f,0.f,0.f);
      if(c < N) v = *(const float4*)(Bm + (size_t)(k0+r)*ldb + c);
      *(float4*)&Bs[r][c4*4] = v;
    }
    __syncthreads();
    #pragma unroll
    for(int kk=0; kk<BK; kk++){
      float4 b = *(const float4*)&Bs[kk][tx*4];
      if constexpr (TM==4){
        float4 a = *(const float4*)&As[kk][ty*4];
        acc[0].x=fmaf(a.x,b.x,acc[0].x); acc[0].y=fmaf(a.x,b.y,acc[0].y); acc[0].z=fmaf(a.x,b.z,acc[0].z); acc[0].w=fmaf(a.x,b.w,acc[0].w);
        acc[1].x=fmaf(a.y,b.x,acc[1].x); acc[1].y=fmaf(a.y,b.y,acc[1].y); acc[1].z=fmaf(a.y,b.z,acc[1].z); acc[1].w=fmaf(a.y,b.w,acc[1].w);
        acc[2].x=fmaf(a.z,b.x,acc[2].x); acc[2].y=fmaf(a.z,b.y,acc[2].y); acc[2].z=fmaf(a.z,b.z,acc[2].z); acc[2].w=fmaf(a.z,b.w,acc[2].w);
        acc[3].x=fmaf(a.w,b.x,acc[3].x); acc[3].y=fmaf(a.w,b.y,acc[3].y); acc[3].z=fmaf(a.w,b.z,acc[3].z); acc[3].w=fmaf(a.w,b.w,acc[3].w);
      } else if constexpr (TM==2){
        float2 a = *(const float2*)&As[kk][ty*2];
        acc[0].x=fmaf(a.x,b.x,acc[0].x); acc[0].y=fmaf(a.x,b.y,acc[0].y); acc[0].z=fmaf(a.x,b.z,acc[0].z); acc[0].w=fmaf(a.x,b.w,acc[0].w);
        acc[1].x=fmaf(a.y,b.x,acc[1].x); acc[1].y=fmaf(a.y,b.y,acc[1].y); acc[1].z=fmaf(a.y,b.z,acc[1].z); acc[1].w=fmaf(a.y,b.w,acc[1].w);
      } else {
        float a = As[kk][ty];
        acc[0].x=fmaf(a,b.x,acc[0].x); acc[0].y=fmaf(a,b.y,acc[0].y); acc[0].z=fmaf(a,b.z,acc[0].z); acc[0].w=fmaf(a,b.w,acc[0].w);
      }
    }
    __syncthreads();
  }
  int c = col0 + tx*4;
  if(c >= N) return;
  #pragma unroll
  for(int i=0;i<TM;i++){
    int r = row0 + ty*TM + i;
    float4 v = acc[i];
    if(Cadd){
      float4 cv = *(const float4*)&Cadd[(size_t)(r & rowmask)*ldcadd + c];
      v.x+=cv.x; v.y+=cv.y; v.z+=cv.z; v.w+=cv.w;
    }
    if(bias){
      float4 bv = *(const float4*)&bias[c];
      v.x+=bv.x; v.y+=bv.y; v.z+=bv.z; v.w+=bv.w;
    }
    if(c < relu_cut){
      v.x=fmaxf(v.x,0.f); v.y=fmaxf(v.y,0.f); v.z=fmaxf(v.z,0.f); v.w=fmaxf(v.w,0.f);
    }
    *(float4*)&Cm[(size_t)r*ldc + c] = v;
  }
}

// ---- weight packing (rebuilt every launch; graph-captured) ----
// WB1[1024][2560] = [Wenc1 | Wpr1(rows<512 else 0) | Whh1(rows<512 else 0)]
__global__ void k_pack1(const float* __restrict__ We1, const float* __restrict__ Wp1,
                        const float* __restrict__ Wh1, float* __restrict__ WB1){
  int i = blockIdx.x*256 + threadIdx.x;
  if(i >= 1024*2560) return;
  int r = i/2560, cc = i%2560;
  float v;
  if(cc < 512)        v = We1[(size_t)r*512 + cc];
  else if(cc < 1024)  v = (r<512) ? Wp1[(size_t)r*512 + (cc-512)] : 0.f;
  else                v = (r<512) ? Wh1[(size_t)r*1536 + (cc-1024)] : 0.f;
  WB1[i] = v;
}
// WB2[1024][512] = blockdiag(Wenc2[512][256], Wpr2[512][256]); plus bias packs
__global__ void k_pack2(const float* __restrict__ We2, const float* __restrict__ Wp2,
                        float* __restrict__ WB2,
                        const float* __restrict__ be1, const float* __restrict__ bp1,
                        const float* __restrict__ bh1, float* __restrict__ bb1,
                        const float* __restrict__ be2, const float* __restrict__ bp2,
                        float* __restrict__ bb2){
  int i = blockIdx.x*256 + threadIdx.x;
  if(i < 1024*512){
    int r = i/512, cc = i%512;
    float v = 0.f;
    if(r<512 && cc<256)       v = We2[(size_t)r*256 + cc];
    else if(r>=512 && cc>=256) v = Wp2[(size_t)(r-512)*256 + (cc-256)];
    WB2[i] = v;
  }
  if(i < 2560) bb1[i] = (i<512)? be1[i] : (i<1024)? bp1[i-512] : bh1[i-1024];
  if(i < 512)  bb2[i] = (i<256)? be2[i] : bp2[i-256];
}

__global__ void k_init(float* S, float* sym){
  int t=threadIdx.x; if(t<5) S[t]=0.f; if(t<48) sym[t]=0.f;
}

__global__ void k_copy(const float* __restrict__ s, float* __restrict__ d, int n4){
  int i=blockIdx.x*blockDim.x+threadIdx.x;
  if(i<n4) ((float4*)d)[i]=((const float4*)s)[i];
}

// kacc += 0.5*sum(kld_e(enc,sp(enc),pri,sp(pri)));  zt = eps*sp(enc)+enc
// enc/pri addressed as encp[b*lde+c] / prip[b*ldp+c], c in [0,Z)
__global__ void k_kldzt(const float* __restrict__ encp, int lde,
                        const float* __restrict__ prip, int ldp,
                        const float* __restrict__ eps, float* __restrict__ zt,
                        float* kacc, int B_, int Z_){
  float loc=0.f;
  int n = B_*Z_;
  for(int i=blockIdx.x*blockDim.x+threadIdx.x; i<n; i+=gridDim.x*blockDim.x){
    int b=i/Z_, cidx=i%Z_;
    float m1=encp[(size_t)b*lde+cidx], m2=prip[(size_t)b*ldp+cidx];
    float s1=sp_(m1), s2=sp_(m2);
    loc += kld_(m1,s1,m2,s2);
    zt[i] = fmaf(eps[i], s1, m1);
  }
  loc = blockReduceSum(loc);
  if(threadIdx.x==0) atomicAdd(kacc, 0.5f*loc);
}

__global__ void k_expand(const float* __restrict__ mean, const float* __restrict__ eps,
                         float* __restrict__ out, int per, int total){
  int i = blockIdx.x*blockDim.x+threadIdx.x;
  if(i<total){
    float m = mean[i % per];
    out[i] = fmaf(eps[i], sp_(m), m);
  }
}

__global__ void k_sym(const float* __restrict__ om, const float* __restrict__ en,
                      float* sym, int n){
  int a = blockIdx.y;
  const float* e = en + (size_t)a*n;
  float loc=0.f;
  for(int i=blockIdx.x*blockDim.x+threadIdx.x; i<n; i+=gridDim.x*blockDim.x){
    float m1=om[i], m2=e[i];
    float s1=sp_(m1), s2=sp_(m2);
    float d=m1-m2, d2=d*d, q1=s1*s1, q2=s2*s2;
    loc += (q1+d2)/q2 + (q2+d2)/q1 - 2.f;
  }
  loc = blockReduceSum(loc);
  if(threadIdx.x==0) atomicAdd(&sym[a], 0.5f*loc);
}

__global__ void k_argmin(const float* sym, int n, int* jsel, float* dis, int add){
  if(threadIdx.x==0 && blockIdx.x==0){
    float m=sym[0]; int j=0;
    for(int a=1;a<n;a++) if(sym[a]<m){m=sym[a];j=a;}
    *jsel=j;
    if(add) *dis += m; else *dis = m;
  }
}

__global__ void k_kldsel(const float* __restrict__ en, const float* __restrict__ pn,
                         const int* jsel, int per, float* out){
  size_t base = (size_t)(*jsel)*per;
  float loc=0.f;
  for(int i=blockIdx.x*blockDim.x+threadIdx.x; i<per; i+=gridDim.x*blockDim.x){
    float m1=en[base+i], m2=pn[base+i];
    loc += kld_(m1, sp_(m1), m2, sp_(m2));
  }
  loc=blockReduceSum(loc);
  if(threadIdx.x==0) atomicAdd(out, 0.5f*loc);
}

__global__ void k_gather(const float* __restrict__ src, const int* jsel,
                         float* __restrict__ dst, int per){
  int i=blockIdx.x*blockDim.x+threadIdx.x;
  if(i<per) dst[i]=src[(size_t)(*jsel)*per+i];
}

// PyTorch GRU gate math, h updated in place; gi/gh have independent strides
__global__ void k_gru(const float* __restrict__ gi, int ldgi,
                      const float* __restrict__ gh, int ldgh,
                      float* __restrict__ h, int B_, int H_){
  int i=blockIdx.x*blockDim.x+threadIdx.x;
  if(i<B_*H_){
    int b=i/H_, c=i%H_;
    const float* gib=gi+(size_t)b*ldgi;
    const float* ghb=gh+(size_t)b*ldgh;
    float r=sig_(gib[c]+ghb[c]);
    float u=sig_(gib[H_+c]+ghb[H_+c]);
    float nn=tanhf(fmaf(r, ghb[2*H_+c], gib[2*H_+c]));
    h[i]=(1.f-u)*nn + u*h[i];
  }
}

extern "C" void kernel_launch(void* const* d_in, const int* in_sizes, int n_in,
                              void* d_out, int out_size, void* d_ws, size_t ws_size,
                              hipStream_t stream)
{
  const int T=32, B=512, F=512, H=512, Z=256, G=3, A=10, C=1000;
  const float* feat   = (const float*)d_in[0];
  const float* h0     = (const float*)d_in[1];
  const float* eps_z  = (const float*)d_in[2];
  const float* eps_g  = (const float*)d_in[3];
  const float* eps_n  = (const float*)d_in[4];
  const float* eps_f  = (const float*)d_in[5];
  const float* Wpx=(const float*)d_in[6],  *bpx=(const float*)d_in[7];
  const float* Wenc1=(const float*)d_in[8],*benc1=(const float*)d_in[9];
  const float* Wenc2=(const float*)d_in[10],*benc2=(const float*)d_in[11];
  const float* Wpr1=(const float*)d_in[12],*bpr1=(const float*)d_in[13];
  const float* Wpr2=(const float*)d_in[14],*bpr2=(const float*)d_in[15];
  const float* Wpz=(const float*)d_in[16], *bpz=(const float*)d_in[17];
  const float* Wih1=(const float*)d_in[18],*Whh1=(const float*)d_in[19];
  const float* bih1=(const float*)d_in[20],*bhh1=(const float*)d_in[21];
  const float* Wzn=(const float*)d_in[22], *bzn=(const float*)d_in[23];
  const float* Wprn1=(const float*)d_in[24],*bprn1=(const float*)d_in[25];
  const float* Wprn2=(const float*)d_in[26],*bprn2=(const float*)d_in[27];
  const float* Wga=(const float*)d_in[28], *bga=(const float*)d_in[29];
  const float* Woa1=(const float*)d_in[30],*boa1=(const float*)d_in[31];
  const float* Woa2=(const float*)d_in[32],*boa2=(const float*)d_in[33];
  const float* Wna1=(const float*)d_in[34],*bna1=(const float*)d_in[35];
  const float* Wna2=(const float*)d_in[36],*bna2=(const float*)d_in[37];
  const float* Wen=(const float*)d_in[38], *ben=(const float*)d_in[39];
  const float* Wact=(const float*)d_in[40],*bact=(const float*)d_in[41];
  const float* Wih2=(const float*)d_in[42],*Whh2=(const float*)d_in[43];
  const float* bih2=(const float*)d_in[44],*bhh2=(const float*)d_in[45];
  const float* Wcc=(const float*)d_in[46], *bcc=(const float*)d_in[47];
  const float* Wnc=(const float*)d_in[48], *bnc=(const float*)d_in[49];

  float* ws = (float*)d_ws;
  size_t off = 0;
  auto alloc = [&](size_t n){ float* p = ws + off; off += n; return p; };
  // ---- base buffers ----
  float* Hb  = alloc((size_t)B*H);
  float* E1  = alloc((size_t)B*H);
  float* P1  = alloc((size_t)B*H);
  float* ZP  = alloc((size_t)B*H);
  float* NM  = alloc((size_t)B*H);
  float* OA  = alloc((size_t)B*H);
  float* PAb = alloc((size_t)B*H);
  float* CAb = alloc((size_t)B*H);
  float* GI  = alloc((size_t)B*3*H);
  float* GH  = alloc((size_t)B*3*H);
  float* ENC = alloc((size_t)B*Z);
  float* PRI = alloc((size_t)B*Z);
  float* ZT  = alloc((size_t)B*Z);
  float* OM  = alloc((size_t)B*Z);
  float* PNH = alloc((size_t)B*Z);
  float* OAZ = alloc((size_t)B*Z);
  float* BASE= alloc((size_t)B*Z);
  float* NACT= alloc((size_t)A*B*H);
  float* PMID= alloc((size_t)A*B*H);
  float* PNX = alloc((size_t)A*B*Z);
  float* ENCN= alloc((size_t)A*B*Z);
  float* BUFA= alloc((size_t)B*H);   // next_act_final  (BUFA/B/C contiguous!)
  float* BUFB= alloc((size_t)B*H);   // future step 0
  float* BUFC= alloc((size_t)B*H);   // future step 1
  float* SYM = alloc(16);
  float* SYMF0 = alloc(16);
  float* SYMF1 = alloc(16);
  int*   JSEL = (int*)alloc(16);
  // ---- packed weights + fused step outputs (optional tier) ----
  size_t base_off = off;
  float* WB1 = alloc((size_t)1024*2560);
  float* bb1 = alloc(2560);
  float* WB2 = alloc((size_t)1024*512);
  float* bb2 = alloc(512);
  float* C1  = alloc((size_t)B*2560);   // [e1 | p1 | gh]
  float* C2  = alloc((size_t)B*512);    // [enc | pri]
  bool packed = off*4 <= ws_size;
  if(!packed) off = base_off;
  size_t phix_off = off;
  float* PHIX = alloc((size_t)T*B*H);
  bool bigphix = off*4 <= ws_size;
  float* XP = nullptr;
  if(!bigphix){ off = phix_off; XP = alloc((size_t)B*H); PHIX = nullptr; }

  float* outCur = (float*)d_out;
  float* outFut = outCur + (size_t)B*C;
  float* S      = outCur + (size_t)B*C*4;

  auto gemm = [&](const float* A1,int lda1,int K1,
                  const float* A2,int lda2,int K2,
                  const float* Bw,int ldb, const float* bias,
                  const float* Cadd,int rowmask,int ldcadd,
                  float* Cm,int ldc,int M,int N,int relu){
    int nb = (N+63)/64;
    int cut = relu ? N : 0;
    if(M%64==0 && (M/64)*nb >= 160){
      dim3 g(nb, M/64);
      gemm_k<64><<<g,256,0,stream>>>(A1,lda1,K1, A2?A2:A1,lda2,K2, Bw,ldb,bias,
                                     Cadd,rowmask,ldcadd, Cm,ldc,N,cut);
    } else if(M%32==0 && (M/32)*nb >= 96){
      dim3 g(nb, M/32);
      gemm_k<32><<<g,256,0,stream>>>(A1,lda1,K1, A2?A2:A1,lda2,K2, Bw,ldb,bias,
                                     Cadd,rowmask,ldcadd, Cm,ldc,N,cut);
    } else {
      dim3 g(nb, M/16);
      gemm_k<16><<<g,256,0,stream>>>(A1,lda1,K1, A2?A2:A1,lda2,K2, Bw,ldb,bias,
                                     Cadd,rowmask,ldcadd, Cm,ldc,N,cut);
    }
  };
  // fused G1 variant with partial relu (cols < cut)
  auto gemm_cut = [&](const float* A1,int lda1,int K1,
                      const float* A2,int lda2,int K2,
                      const float* Bw,int ldb, const float* bias,
                      float* Cm,int ldc,int M,int N,int cut){
    dim3 g((N+63)/64, M/64);
    gemm_k<64><<<g,256,0,stream>>>(A1,lda1,K1, A2?A2:A1,lda2,K2, Bw,ldb,bias,
                                   (const float*)0,0,0, Cm,ldc,N,cut);
  };
  auto ew = [&](int n){ return dim3((n+255)/256); };

  k_init<<<1,64,0,stream>>>(S, SYM);
  k_copy<<<ew(B*H/4),256,0,stream>>>(h0, Hb, B*H/4);
  if(packed){
    k_pack1<<<(1024*2560+255)/256,256,0,stream>>>(Wenc1,Wpr1,Whh1,WB1);
    k_pack2<<<(1024*512+255)/256,256,0,stream>>>(Wenc2,Wpr2,WB2, benc1,bpr1,bhh1,bb1, benc2,bpr2,bb2);
  }
  if(bigphix)
    gemm(feat,F,F, 0,0,0, Wpx,H,bpx, 0,0,0, PHIX,H, T*B,H, 1);

  // ---- scan over T steps ----
  for(int t=0;t<T;t++){
    const float* xp;
    if(bigphix) xp = PHIX + (size_t)t*B*H;
    else { gemm(feat+(size_t)t*B*F,F,F, 0,0,0, Wpx,H,bpx, 0,0,0, XP,H, B,H, 1); xp = XP; }
    const float* epz = eps_z + (size_t)t*B*Z;
    if(packed){
      // C1 = [relu([h|xp]@Wenc1) | relu(h@Wpr1) | h@Whh1], one GEMM N=2560
      gemm_cut(Hb,H,H, xp,H,H, WB1,2560, bb1, C1,2560, B,2560, 1024);
      // C2 = [enc | pri], one GEMM K=1024 (blockdiag)
      gemm(C1,2560,1024, 0,0,0, WB2,512, bb2, 0,0,0, C2,512, B,512, 0);
      k_kldzt<<<128,256,0,stream>>>(C2,512, C2+256,512, epz, ZT, &S[0], B, Z);
      gemm(ZT,Z,Z, 0,0,0, Wpz,H,bpz, 0,0,0, ZP,H, B,H, 1);
      gemm(xp,H,H, ZP,H,H, Wih1,3*H,bih1, 0,0,0, GI,3*H, B,3*H, 0);
      k_gru<<<ew(B*H),256,0,stream>>>(GI,3*H, C1+1024,2560, Hb,B,H);
    } else {
      gemm(Hb,H,H, xp,H,H, Wenc1,H,benc1, 0,0,0, E1,H, B,H, 1);
      gemm(E1,H,H, 0,0,0, Wenc2,Z,benc2, 0,0,0, ENC,Z, B,Z, 0);
      gemm(Hb,H,H, 0,0,0, Wpr1,H,bpr1, 0,0,0, P1,H, B,H, 1);
      gemm(P1,H,H, 0,0,0, Wpr2,Z,bpr2, 0,0,0, PRI,Z, B,Z, 0);
      k_kldzt<<<128,256,0,stream>>>(ENC,Z, PRI,Z, epz, ZT, &S[0], B, Z);
      gemm(ZT,Z,Z, 0,0,0, Wpz,H,bpz, 0,0,0, ZP,H, B,H, 1);
      gemm(xp,H,H, ZP,H,H, Wih1,3*H,bih1, 0,0,0, GI,3*H, B,3*H, 0);
      gemm(Hb,H,H, 0,0,0, Whh1,3*H,bhh1, 0,0,0, GH,3*H, B,3*H, 0);
      k_gru<<<ew(B*H),256,0,stream>>>(GI,3*H, GH,3*H, Hb,B,H);
    }
  }

  // ---- phase 3: only g = G-1 reaches any output ----
  gemm(Hb,H,H, 0,0,0, Wpr1,H,bpr1, 0,0,0, P1,H, B,H, 1);
  gemm(P1,H,H, 0,0,0, Wpr2,Z,bpr2, 0,0,0, OM,Z, B,Z, 0);            // obs_mean
  gemm(Hb,H,H, 0,0,0, Wprn1,H,bprn1, 0,0,0, P1,H, B,H, 1);
  gemm(P1,H,H, 0,0,0, Wprn2,Z,bprn2, 0,0,0, PNH,Z, B,Z, 0);         // pn_h
  k_expand<<<ew(B*Z),256,0,stream>>>(OM, eps_g+(size_t)(G-1)*B*Z, ZT, B*Z, B*Z);
  gemm(ZT,Z,Z, 0,0,0, Wzn,H,bzn, 0,0,0, E1,H, B,H, 1);              // zn
  gemm(E1,H,H, PNH,Z,Z, Wga,H,bga, 0,0,0, OA,H, B,H, 1);            // obs_act
  gemm(PNH,Z,Z, OA,H,H, Wga,H,bga, 0,0,0, NM,H, B,H, 1);            // next_mean
  k_expand<<<ew(A*B*H),256,0,stream>>>(NM, eps_n+(size_t)(G-1)*A*B*H, NACT, B*H, A*B*H);
  gemm(NACT,H,H, 0,0,0, Wna1,H,bna1, 0,0,0, PMID,H, A*B,H, 1);
  gemm(PMID,H,H, 0,0,0, Wna2,Z,bna2, 0,0,0, PNX,Z, A*B,Z, 0);       // pnext
  gemm(OA,H,H, 0,0,0, Woa1,H,boa1, 0,0,0, P1,H, B,H, 1);
  gemm(P1,H,H, 0,0,0, Woa2,Z,boa2, 0,0,0, OAZ,Z, B,Z, 0);           // obs_act_z
  gemm(OAZ,Z,Z, 0,0,0, Wen+(size_t)Z*Z,Z, ben, 0,0,0, BASE,Z, B,Z, 0);
  gemm(PNX,Z,Z, 0,0,0, Wen,Z, 0, BASE,B-1,Z, ENCN,Z, A*B,Z, 1);     // enc_next
  k_sym<<<dim3(32,A),256,0,stream>>>(OM, ENCN, SYM, B*Z);
  k_argmin<<<1,64,0,stream>>>(SYM, A, &JSEL[0], &S[2], 0);
  k_kldsel<<<128,256,0,stream>>>(ENCN, PNX, &JSEL[0], B*Z, &S[1]);
  k_gather<<<ew(B*H),256,0,stream>>>(NACT, &JSEL[0], BUFA, B*H);

  // ---- phase 4: 2 future steps ----
  const float* pre = OA; const float* cur = BUFA;
  float* futbuf[2] = {BUFB, BUFC};
  for(int i=0;i<2;i++){
    gemm(pre,H,H, 0,0,0, Wact,H,bact, 0,0,0, PAb,H, B,H, 1);
    gemm(cur,H,H, 0,0,0, Wact,H,bact, 0,0,0, CAb,H, B,H, 1);
    gemm(PAb,H,H, CAb,H,H, Wih2,3*H,bih2, 0,0,0, GI,3*H, B,3*H, 0);
    gemm(Hb,H,H, 0,0,0, Whh2,3*H,bhh2, 0,0,0, GH,3*H, B,3*H, 0);
    k_gru<<<ew(B*H),256,0,stream>>>(GI,3*H, GH,3*H, Hb,B,H);
    pre = cur;
    gemm(Hb,H,H, 0,0,0, Wprn1,H,bprn1, 0,0,0, P1,H, B,H, 1);
    gemm(P1,H,H, 0,0,0, Wprn2,Z,bprn2, 0,0,0, PNH,Z, B,Z, 0);
    gemm(PNH,Z,Z, pre,H,H, Wga,H,bga, 0,0,0, NM,H, B,H, 1);         // fmean
    k_expand<<<ew(A*B*H),256,0,stream>>>(NM, eps_f+(size_t)i*A*B*H, NACT, B*H, A*B*H);
    gemm(NACT,H,H, 0,0,0, Wna1,H,bna1, 0,0,0, PMID,H, A*B,H, 1);
    gemm(PMID,H,H, 0,0,0, Wna2,Z,bna2, 0,0,0, PNX,Z, A*B,Z, 0);     // pf
    gemm(pre,H,H, 0,0,0, Wna1,H,bna1, 0,0,0, P1,H, B,H, 1);
    gemm(P1,H,H, 0,0,0, Wna2,Z,bna2, 0,0,0, OAZ,Z, B,Z, 0);         // pre_z
    gemm(OAZ,Z,Z, 0,0,0, Wen+(size_t)Z*Z,Z, ben, 0,0,0, BASE,Z, B,Z, 0);
    gemm(PNX,Z,Z, 0,0,0, Wen,Z, 0, BASE,B-1,Z, ENCN,Z, A*B,Z, 1);   // encf
    float* symf = (i==0)?SYMF0:SYMF1;
    k_sym<<<dim3(32,A),256,0,stream>>>(OM, ENCN, symf, B*Z);
    k_argmin<<<1,64,0,stream>>>(symf, A, &JSEL[1+i], &S[4], 1);
    k_kldsel<<<128,256,0,stream>>>(ENCN, PNX, &JSEL[1+i], B*Z, &S[3]);
    k_gather<<<ew(B*H),256,0,stream>>>(NACT, &JSEL[1+i], futbuf[i], B*H);
    cur = futbuf[i];
  }

  // ---- outputs: out_cur, and all 3 future rows in ONE M=1536 GEMM ----
  gemm(OA,H,H, 0,0,0, Wcc,C,bcc, 0,0,0, outCur,C, B,C, 0);
  gemm(BUFA,H,H, 0,0,0, Wnc,C,bnc, 0,0,0, outFut,C, 3*B,C, 0);
}

// Round 4
// 4375.781 us; speedup vs baseline: 2.4483x; 1.7944x over previous
//
#include <hip/hip_runtime.h>
#include <math.h>

#define DEV __device__ __forceinline__

typedef unsigned short ushort_t;
typedef __attribute__((ext_vector_type(8))) short s8v;    // 8 x bf16 (4 VGPR)
typedef __attribute__((ext_vector_type(4))) float f4v;    // MFMA acc

DEV float sp_(float x){ float m=fmaxf(x,0.f); return m + log1pf(expf(-fabsf(x))); }
DEV float sig_(float x){ return 1.f/(1.f+expf(-x)); }
DEV float kld_(float m1,float s1,float m2,float s2){
  float d=m1-m2;
  return 2.f*(logf(s2)-logf(s1)) + (s1*s1+d*d)/(s2*s2) - 1.f;
}
DEV unsigned short f2bf(float x){
  unsigned u = __float_as_uint(x);
  u += 0x7FFFu + ((u>>16)&1u);       // round-to-nearest-even
  return (unsigned short)(u>>16);
}

DEV float blockReduceSum(float v){
  __shared__ float sh[8];
  #pragma unroll
  for(int o=32;o>0;o>>=1) v += __shfl_down(v,o,64);
  int lane = threadIdx.x & 63, wid = threadIdx.x >> 6;
  if(lane==0) sh[wid]=v;
  __syncthreads();
  float r = 0.f;
  if(threadIdx.x < (int)(blockDim.x>>6)) r = sh[threadIdx.x];
  if(wid==0){
    #pragma unroll
    for(int o=4;o>0;o>>=1) r += __shfl_down(r,o,64);
  }
  return r;
}

// ============================ MFMA bf16 GEMM ============================
// C = epilogue( A @ B ) where A = virtual K-concat [A1|A2] (fp32, converted
// to bf16 on the fly), B given as pre-transposed bf16 BT[N][K] (ldbt).
// Tile 64x64, BK=32, 256 threads = 4 waves, each wave one 32x32 subtile
// (2x2 of 16x16x32 MFMA). M % 64 == 0 required; K % 32 == 0; K1 % 8 == 0.
__global__ __launch_bounds__(256)
void gemm_mf(const float* __restrict__ A1, int lda1, int K1,
             const float* __restrict__ A2, int lda2, int K2,
             const ushort_t* __restrict__ BT, int ldbt,
             const float* __restrict__ bias,
             const float* __restrict__ Cadd, int rowmask, int ldcadd,
             float* __restrict__ Cm, int ldc, int N, int relu_cut)
{
  __shared__ ushort_t As[64][40];   // +8 pad: 2-way bank alias only (free)
  __shared__ ushort_t Bs[64][40];
  const int tid  = threadIdx.x;
  const int row0 = blockIdx.y * 64;
  const int col0 = blockIdx.x * 64;
  const int lane = tid & 63;
  const int w    = tid >> 6;
  const int wr   = w >> 1, wc = w & 1;
  const int Kt   = K1 + K2;
  f4v acc[2][2];
  #pragma unroll
  for(int i=0;i<2;i++){
    #pragma unroll
    for(int j=0;j<2;j++){ acc[i][j][0]=0.f; acc[i][j][1]=0.f; acc[i][j][2]=0.f; acc[i][j][3]=0.f; }
  }
  const int sr  = tid >> 2;          // 0..63 staging row (A-row / B-col)
  const int skc = (tid & 3) * 8;     // 0,8,16,24 k-chunk

  for(int k0=0; k0<Kt; k0+=32){
    // ---- stage A: fp32 -> bf16 ----
    int kg = k0 + skc;
    const float* ap = (kg < K1) ? (A1 + (size_t)(row0+sr)*lda1 + kg)
                                : (A2 + (size_t)(row0+sr)*lda2 + (kg-K1));
    float4 v0 = *(const float4*)ap;
    float4 v1 = *(const float4*)(ap+4);
    s8v av;
    av[0]=(short)f2bf(v0.x); av[1]=(short)f2bf(v0.y); av[2]=(short)f2bf(v0.z); av[3]=(short)f2bf(v0.w);
    av[4]=(short)f2bf(v1.x); av[5]=(short)f2bf(v1.y); av[6]=(short)f2bf(v1.z); av[7]=(short)f2bf(v1.w);
    *(s8v*)&As[sr][skc] = av;
    // ---- stage B: bf16 direct (row of BT = one output column) ----
    int cb = col0 + sr;
    s8v bv = {0,0,0,0,0,0,0,0};
    if(cb < N) bv = *(const s8v*)(BT + (size_t)cb*ldbt + k0 + skc);
    *(s8v*)&Bs[sr][skc] = bv;
    __syncthreads();
    // ---- fragments + MFMA ----
    const int fr = lane & 15, fk = (lane >> 4) * 8;
    s8v a0 = *(const s8v*)&As[wr*32      + fr][fk];
    s8v a1 = *(const s8v*)&As[wr*32 + 16 + fr][fk];
    s8v b0 = *(const s8v*)&Bs[wc*32      + fr][fk];
    s8v b1 = *(const s8v*)&Bs[wc*32 + 16 + fr][fk];
    acc[0][0] = __builtin_amdgcn_mfma_f32_16x16x32_bf16(a0,b0,acc[0][0],0,0,0);
    acc[0][1] = __builtin_amdgcn_mfma_f32_16x16x32_bf16(a0,b1,acc[0][1],0,0,0);
    acc[1][0] = __builtin_amdgcn_mfma_f32_16x16x32_bf16(a1,b0,acc[1][0],0,0,0);
    acc[1][1] = __builtin_amdgcn_mfma_f32_16x16x32_bf16(a1,b1,acc[1][1],0,0,0);
    __syncthreads();
  }
  // ---- epilogue: D layout col=lane&15, row=(lane>>4)*4+reg ----
  const int fr = lane & 15, fq = lane >> 4;
  #pragma unroll
  for(int fi=0; fi<2; fi++){
    #pragma unroll
    for(int fj=0; fj<2; fj++){
      int col = col0 + wc*32 + fj*16 + fr;
      if(col >= N) continue;
      #pragma unroll
      for(int r=0;r<4;r++){
        int row = row0 + wr*32 + fi*16 + fq*4 + r;
        float v = acc[fi][fj][r];
        if(Cadd) v += Cadd[(size_t)(row & rowmask)*ldcadd + col];
        if(bias) v += bias[col];
        if(col < relu_cut) v = fmaxf(v, 0.f);
        Cm[(size_t)row*ldc + col] = v;
      }
    }
  }
}

// ===================== fp32 vector GEMM (SAFE fallback) =====================
template<int BM>
__global__ __launch_bounds__(256)
void gemm_k(const float* __restrict__ A1, int lda1, int K1,
            const float* __restrict__ A2, int lda2, int K2,
            const float* __restrict__ Bm, int ldb,
            const float* __restrict__ bias,
            const float* __restrict__ Cadd, int rowmask, int ldcadd,
            float* __restrict__ Cm, int ldc, int N, int relu_cut)
{
  constexpr int BN = 64, BK = 32;
  constexpr int TM = BM/16;
  constexpr int PAD = (BM>=32) ? 4 : 1;
  __shared__ float As[BK][BM+PAD];
  __shared__ float Bs[BK][BN];
  const int tid = threadIdx.x;
  const int row0 = blockIdx.y * BM;
  const int col0 = blockIdx.x * BN;
  const int tx = tid & 15, ty = tid >> 4;
  float4 acc[TM];
  #pragma unroll
  for(int i=0;i<TM;i++) acc[i] = make_float4(0.f,0.f,0.f,0.f);
  const int Kt = K1 + K2;
  for(int k0=0; k0<Kt; k0+=BK){
    if constexpr (BM>=32){
      #pragma unroll
      for(int j=0;j<BM/32;j++){
        int ci = tid + j*256;
        int r  = ci >> 3;
        int kq = ci & 7;
        int kg = k0 + kq*4;
        const float* ap = (kg < K1) ? (A1 + (size_t)(row0+r)*lda1 + kg)
                                    : (A2 + (size_t)(row0+r)*lda2 + (kg-K1));
        float4 v = *(const float4*)ap;
        As[kq*4+0][r]=v.x; As[kq*4+1][r]=v.y; As[kq*4+2][r]=v.z; As[kq*4+3][r]=v.w;
      }
    } else {
      int r  = tid >> 4;
      int kq = tid & 15;
      int kg = k0 + kq*2;
      const float* ap = (kg < K1) ? (A1 + (size_t)(row0+r)*lda1 + kg)
                                  : (A2 + (size_t)(row0+r)*lda2 + (kg-K1));
      float2 v = *(const float2*)ap;
      As[kq*2+0][r]=v.x; As[kq*2+1][r]=v.y;
    }
    #pragma unroll
    for(int j=0;j<2;j++){
      int ci = tid + j*256;
      int r = ci >> 4, c4 = ci & 15;
      int c = col0 + c4*4;
      float4 v = make_float4(0.f,0.f,0.f,0.f);
      if(c < N) v = *(const float4*)(Bm + (size_t)(k0+r)*ldb + c);
      *(float4*)&Bs[r][c4*4] = v;
    }
    __syncthreads();
    #pragma unroll
    for(int kk=0; kk<BK; kk++){
      float4 b = *(const float4*)&Bs[kk][tx*4];
      if constexpr (TM==4){
        float4 a = *(const float4*)&As[kk][ty*4];
        acc[0].x=fmaf(a.x,b.x,acc[0].x); acc[0].y=fmaf(a.x,b.y,acc[0].y); acc[0].z=fmaf(a.x,b.z,acc[0].z); acc[0].w=fmaf(a.x,b.w,acc[0].w);
        acc[1].x=fmaf(a.y,b.x,acc[1].x); acc[1].y=fmaf(a.y,b.y,acc[1].y); acc[1].z=fmaf(a.y,b.z,acc[1].z); acc[1].w=fmaf(a.y,b.w,acc[1].w);
        acc[2].x=fmaf(a.z,b.x,acc[2].x); acc[2].y=fmaf(a.z,b.y,acc[2].y); acc[2].z=fmaf(a.z,b.z,acc[2].z); acc[2].w=fmaf(a.z,b.w,acc[2].w);
        acc[3].x=fmaf(a.w,b.x,acc[3].x); acc[3].y=fmaf(a.w,b.y,acc[3].y); acc[3].z=fmaf(a.w,b.z,acc[3].z); acc[3].w=fmaf(a.w,b.w,acc[3].w);
      } else if constexpr (TM==2){
        float2 a = *(const float2*)&As[kk][ty*2];
        acc[0].x=fmaf(a.x,b.x,acc[0].x); acc[0].y=fmaf(a.x,b.y,acc[0].y); acc[0].z=fmaf(a.x,b.z,acc[0].z); acc[0].w=fmaf(a.x,b.w,acc[0].w);
        acc[1].x=fmaf(a.y,b.x,acc[1].x); acc[1].y=fmaf(a.y,b.y,acc[1].y); acc[1].z=fmaf(a.y,b.z,acc[1].z); acc[1].w=fmaf(a.y,b.w,acc[1].w);
      } else {
        float a = As[kk][ty];
        acc[0].x=fmaf(a,b.x,acc[0].x); acc[0].y=fmaf(a,b.y,acc[0].y); acc[0].z=fmaf(a,b.z,acc[0].z); acc[0].w=fmaf(a,b.w,acc[0].w);
      }
    }
    __syncthreads();
  }
  int c = col0 + tx*4;
  if(c >= N) return;
  #pragma unroll
  for(int i=0;i<TM;i++){
    int r = row0 + ty*TM + i;
    float4 v = acc[i];
    if(Cadd){
      float4 cv = *(const float4*)&Cadd[(size_t)(r & rowmask)*ldcadd + c];
      v.x+=cv.x; v.y+=cv.y; v.z+=cv.z; v.w+=cv.w;
    }
    if(bias){
      float4 bv = *(const float4*)&bias[c];
      v.x+=bv.x; v.y+=bv.y; v.z+=bv.z; v.w+=bv.w;
    }
    if(c < relu_cut){
      v.x=fmaxf(v.x,0.f); v.y=fmaxf(v.y,0.f); v.z=fmaxf(v.z,0.f); v.w=fmaxf(v.w,0.f);
    }
    *(float4*)&Cm[(size_t)r*ldc + c] = v;
  }
}

// ===================== weight conversion / packing =====================
// W[K][N] fp32 -> WT[N][K] bf16
__global__ void k_cvtT(const float* __restrict__ W, ushort_t* __restrict__ WT,
                       int K, int N){
  int i = blockIdx.x*256 + threadIdx.x;
  if(i >= K*N) return;
  int k = i / N, n = i % N;
  WT[(size_t)n*K + k] = f2bf(W[i]);
}
// WB1T[2560][1024]: n<512: Wenc1[k][n]; n<1024: k<512? Wpr1[k][n-512]:0;
//                   else:  k<512? Whh1[k][n-1024]:0
__global__ void k_packT1(const float* __restrict__ We1, const float* __restrict__ Wp1,
                         const float* __restrict__ Wh1, ushort_t* __restrict__ WB1T){
  int i = blockIdx.x*256 + threadIdx.x;
  if(i >= 2560*1024) return;
  int n = i >> 10, k = i & 1023;
  float v;
  if(n < 512)       v = We1[(size_t)k*512 + n];
  else if(n < 1024) v = (k<512) ? Wp1[(size_t)k*512 + (n-512)] : 0.f;
  else              v = (k<512) ? Wh1[(size_t)k*1536 + (n-1024)] : 0.f;
  WB1T[i] = f2bf(v);
}
// WB2T[512][1024] blockdiag(Wenc2, Wpr2) transposed + bias packs (fp32)
__global__ void k_packT2(const float* __restrict__ We2, const float* __restrict__ Wp2,
                         ushort_t* __restrict__ WB2T,
                         const float* __restrict__ be1, const float* __restrict__ bp1,
                         const float* __restrict__ bh1, float* __restrict__ bb1,
                         const float* __restrict__ be2, const float* __restrict__ bp2,
                         float* __restrict__ bb2){
  int i = blockIdx.x*256 + threadIdx.x;
  if(i < 512*1024){
    int n = i >> 10, k = i & 1023;
    float v = 0.f;
    if(n < 256 && k < 512)        v = We2[(size_t)k*256 + n];
    else if(n >= 256 && k >= 512) v = Wp2[(size_t)(k-512)*256 + (n-256)];
    WB2T[i] = f2bf(v);
  }
  if(i < 2560) bb1[i] = (i<512)? be1[i] : (i<1024)? bp1[i-512] : bh1[i-1024];
  if(i < 512)  bb2[i] = (i<256)? be2[i] : bp2[i-256];
}

// ===================== elementwise / reduction kernels =====================
__global__ void k_init(float* S, float* sym){
  int t=threadIdx.x; if(t<5) S[t]=0.f; if(t<48) sym[t]=0.f;
}
__global__ void k_copy(const float* __restrict__ s, float* __restrict__ d, int n4){
  int i=blockIdx.x*blockDim.x+threadIdx.x;
  if(i<n4) ((float4*)d)[i]=((const float4*)s)[i];
}
__global__ void k_kldzt(const float* __restrict__ encp, int lde,
                        const float* __restrict__ prip, int ldp,
                        const float* __restrict__ eps, float* __restrict__ zt,
                        float* kacc, int B_, int Z_){
  float loc=0.f;
  int n = B_*Z_;
  for(int i=blockIdx.x*blockDim.x+threadIdx.x; i<n; i+=gridDim.x*blockDim.x){
    int b=i/Z_, cidx=i%Z_;
    float m1=encp[(size_t)b*lde+cidx], m2=prip[(size_t)b*ldp+cidx];
    float s1=sp_(m1), s2=sp_(m2);
    loc += kld_(m1,s1,m2,s2);
    zt[i] = fmaf(eps[i], s1, m1);
  }
  loc = blockReduceSum(loc);
  if(threadIdx.x==0) atomicAdd(kacc, 0.5f*loc);
}
__global__ void k_expand(const float* __restrict__ mean, const float* __restrict__ eps,
                         float* __restrict__ out, int per, int total){
  int i = blockIdx.x*blockDim.x+threadIdx.x;
  if(i<total){
    float m = mean[i % per];
    out[i] = fmaf(eps[i], sp_(m), m);
  }
}
__global__ void k_sym(const float* __restrict__ om, const float* __restrict__ en,
                      float* sym, int n){
  int a = blockIdx.y;
  const float* e = en + (size_t)a*n;
  float loc=0.f;
  for(int i=blockIdx.x*blockDim.x+threadIdx.x; i<n; i+=gridDim.x*blockDim.x){
    float m1=om[i], m2=e[i];
    float s1=sp_(m1), s2=sp_(m2);
    float d=m1-m2, d2=d*d, q1=s1*s1, q2=s2*s2;
    loc += (q1+d2)/q2 + (q2+d2)/q1 - 2.f;
  }
  loc = blockReduceSum(loc);
  if(threadIdx.x==0) atomicAdd(&sym[a], 0.5f*loc);
}
__global__ void k_argmin(const float* sym, int n, int* jsel, float* dis, int add){
  if(threadIdx.x==0 && blockIdx.x==0){
    float m=sym[0]; int j=0;
    for(int a=1;a<n;a++) if(sym[a]<m){m=sym[a];j=a;}
    *jsel=j;
    if(add) *dis += m; else *dis = m;
  }
}
__global__ void k_kldsel(const float* __restrict__ en, const float* __restrict__ pn,
                         const int* jsel, int per, float* out){
  size_t base = (size_t)(*jsel)*per;
  float loc=0.f;
  for(int i=blockIdx.x*blockDim.x+threadIdx.x; i<per; i+=gridDim.x*blockDim.x){
    float m1=en[base+i], m2=pn[base+i];
    loc += kld_(m1, sp_(m1), m2, sp_(m2));
  }
  loc=blockReduceSum(loc);
  if(threadIdx.x==0) atomicAdd(out, 0.5f*loc);
}
__global__ void k_gather(const float* __restrict__ src, const int* jsel,
                         float* __restrict__ dst, int per){
  int i=blockIdx.x*blockDim.x+threadIdx.x;
  if(i<per) dst[i]=src[(size_t)(*jsel)*per+i];
}
__global__ void k_gru(const float* __restrict__ gi, int ldgi,
                      const float* __restrict__ gh, int ldgh,
                      float* __restrict__ h, int B_, int H_){
  int i=blockIdx.x*blockDim.x+threadIdx.x;
  if(i<B_*H_){
    int b=i/H_, c=i%H_;
    const float* gib=gi+(size_t)b*ldgi;
    const float* ghb=gh+(size_t)b*ldgh;
    float r=sig_(gib[c]+ghb[c]);
    float u=sig_(gib[H_+c]+ghb[H_+c]);
    float nn=tanhf(fmaf(r, ghb[2*H_+c], gib[2*H_+c]));
    h[i]=(1.f-u)*nn + u*h[i];
  }
}

extern "C" void kernel_launch(void* const* d_in, const int* in_sizes, int n_in,
                              void* d_out, int out_size, void* d_ws, size_t ws_size,
                              hipStream_t stream)
{
  const int T=32, B=512, F=512, H=512, Z=256, G=3, A=10, C=1000;
  const float* feat   = (const float*)d_in[0];
  const float* h0     = (const float*)d_in[1];
  const float* eps_z  = (const float*)d_in[2];
  const float* eps_g  = (const float*)d_in[3];
  const float* eps_n  = (const float*)d_in[4];
  const float* eps_f  = (const float*)d_in[5];
  const float* Wpx=(const float*)d_in[6],  *bpx=(const float*)d_in[7];
  const float* Wenc1=(const float*)d_in[8],*benc1=(const float*)d_in[9];
  const float* Wenc2=(const float*)d_in[10],*benc2=(const float*)d_in[11];
  const float* Wpr1=(const float*)d_in[12],*bpr1=(const float*)d_in[13];
  const float* Wpr2=(const float*)d_in[14],*bpr2=(const float*)d_in[15];
  const float* Wpz=(const float*)d_in[16], *bpz=(const float*)d_in[17];
  const float* Wih1=(const float*)d_in[18],*Whh1=(const float*)d_in[19];
  const float* bih1=(const float*)d_in[20],*bhh1=(const float*)d_in[21];
  const float* Wzn=(const float*)d_in[22], *bzn=(const float*)d_in[23];
  const float* Wprn1=(const float*)d_in[24],*bprn1=(const float*)d_in[25];
  const float* Wprn2=(const float*)d_in[26],*bprn2=(const float*)d_in[27];
  const float* Wga=(const float*)d_in[28], *bga=(const float*)d_in[29];
  const float* Woa1=(const float*)d_in[30],*boa1=(const float*)d_in[31];
  const float* Woa2=(const float*)d_in[32],*boa2=(const float*)d_in[33];
  const float* Wna1=(const float*)d_in[34],*bna1=(const float*)d_in[35];
  const float* Wna2=(const float*)d_in[36],*bna2=(const float*)d_in[37];
  const float* Wen=(const float*)d_in[38], *ben=(const float*)d_in[39];
  const float* Wact=(const float*)d_in[40],*bact=(const float*)d_in[41];
  const float* Wih2=(const float*)d_in[42],*Whh2=(const float*)d_in[43];
  const float* bih2=(const float*)d_in[44],*bhh2=(const float*)d_in[45];
  const float* Wcc=(const float*)d_in[46], *bcc=(const float*)d_in[47];
  const float* Wnc=(const float*)d_in[48], *bnc=(const float*)d_in[49];

  float* ws = (float*)d_ws;
  size_t off = 0;
  auto alloc = [&](size_t n){ float* p = ws + off; off += n; return p; };
  // ---- base fp32 buffers ----
  float* Hb  = alloc((size_t)B*H);
  float* E1  = alloc((size_t)B*H);
  float* P1  = alloc((size_t)B*H);
  float* ZP  = alloc((size_t)B*H);
  float* NM  = alloc((size_t)B*H);
  float* OA  = alloc((size_t)B*H);
  float* PAb = alloc((size_t)B*H);
  float* CAb = alloc((size_t)B*H);
  float* GI  = alloc((size_t)B*3*H);
  float* GH  = alloc((size_t)B*3*H);
  float* ENC = alloc((size_t)B*Z);
  float* PRI = alloc((size_t)B*Z);
  float* ZT  = alloc((size_t)B*Z);
  float* OM  = alloc((size_t)B*Z);
  float* PNH = alloc((size_t)B*Z);
  float* OAZ = alloc((size_t)B*Z);
  float* BASE= alloc((size_t)B*Z);
  float* NACT= alloc((size_t)A*B*H);
  float* PMID= alloc((size_t)A*B*H);
  float* PNX = alloc((size_t)A*B*Z);
  float* ENCN= alloc((size_t)A*B*Z);
  float* BUFA= alloc((size_t)B*H);   // next_act_final (BUFA/B/C contiguous)
  float* BUFB= alloc((size_t)B*H);
  float* BUFC= alloc((size_t)B*H);
  float* C1  = alloc((size_t)B*2560);  // [e1 | p1 | gh]
  float* C2  = alloc((size_t)B*512);   // [enc | pri]
  float* bb1 = alloc(2560);
  float* bb2 = alloc(512);
  float* SYM = alloc(16);
  float* SYMF0 = alloc(16);
  float* SYMF1 = alloc(16);
  int*   JSEL = (int*)alloc(16);
  // ---- bf16 weight arena (FAST tier) ----
  size_t mark = off;
  auto ua = [&](size_t n){ ushort_t* p = (ushort_t*)(ws + off); off += n/2; return p; };
  ushort_t* WpxT  = ua((size_t)512*512);
  ushort_t* WB1T  = ua((size_t)2560*1024);
  ushort_t* WB2T  = ua((size_t)512*1024);
  ushort_t* WpzT  = ua((size_t)512*256);
  ushort_t* Wih1T = ua((size_t)1536*1024);
  ushort_t* Wpr1T = ua((size_t)512*512);
  ushort_t* Wpr2T = ua((size_t)256*512);
  ushort_t* Wprn1T= ua((size_t)512*512);
  ushort_t* Wprn2T= ua((size_t)256*512);
  ushort_t* WznT  = ua((size_t)512*256);
  ushort_t* WgaT  = ua((size_t)512*768);
  ushort_t* Woa1T = ua((size_t)512*512);
  ushort_t* Woa2T = ua((size_t)256*512);
  ushort_t* Wna1T = ua((size_t)512*512);
  ushort_t* Wna2T = ua((size_t)256*512);
  ushort_t* WenT  = ua((size_t)256*512);
  ushort_t* WactT = ua((size_t)512*512);
  ushort_t* Wih2T = ua((size_t)1536*1024);
  ushort_t* Whh2T = ua((size_t)1536*512);
  ushort_t* WccT  = ua((size_t)1000*512);
  ushort_t* WncT  = ua((size_t)1000*512);
  bool fast = off*4 <= ws_size;
  if(!fast) off = mark;
  // ---- PHIX tier ----
  size_t mark2 = off;
  float* PHIX = alloc((size_t)T*B*H);
  bool bigphix = off*4 <= ws_size;
  float* XP = nullptr;
  if(!bigphix){ off = mark2; XP = alloc((size_t)B*H); PHIX = nullptr; }

  float* outCur = (float*)d_out;
  float* outFut = outCur + (size_t)B*C;
  float* S      = outCur + (size_t)B*C*4;

  auto ew = [&](int n){ return dim3((n+255)/256); };
  auto cvt = [&](const float* W, ushort_t* WT, int K, int N){
    k_cvtT<<<(K*N+255)/256,256,0,stream>>>(W,WT,K,N);
  };
  // MFMA gemm wrapper
  auto mf = [&](const float* A1,int lda1,int K1,
                const float* A2,int lda2,int K2,
                const ushort_t* BT,int ldbt, const float* bias,
                const float* Cadd,int rowmask,int ldcadd,
                float* Cm,int ldc,int M,int N,int cut){
    dim3 g((N+63)/64, M/64);
    gemm_mf<<<g,256,0,stream>>>(A1,lda1,K1, A2?A2:A1,lda2,K2, BT,ldbt,bias,
                                Cadd,rowmask,ldcadd, Cm,ldc,N,cut);
  };
  // fp32 gemm wrapper (SAFE)
  auto gemm = [&](const float* A1,int lda1,int K1,
                  const float* A2,int lda2,int K2,
                  const float* Bw,int ldb, const float* bias,
                  const float* Cadd,int rowmask,int ldcadd,
                  float* Cm,int ldc,int M,int N,int relu){
    int nb = (N+63)/64;
    int cut = relu ? N : 0;
    if(M%64==0 && (M/64)*nb >= 160){
      dim3 g(nb, M/64);
      gemm_k<64><<<g,256,0,stream>>>(A1,lda1,K1, A2?A2:A1,lda2,K2, Bw,ldb,bias,
                                     Cadd,rowmask,ldcadd, Cm,ldc,N,cut);
    } else if(M%32==0 && (M/32)*nb >= 96){
      dim3 g(nb, M/32);
      gemm_k<32><<<g,256,0,stream>>>(A1,lda1,K1, A2?A2:A1,lda2,K2, Bw,ldb,bias,
                                     Cadd,rowmask,ldcadd, Cm,ldc,N,cut);
    } else {
      dim3 g(nb, M/16);
      gemm_k<16><<<g,256,0,stream>>>(A1,lda1,K1, A2?A2:A1,lda2,K2, Bw,ldb,bias,
                                     Cadd,rowmask,ldcadd, Cm,ldc,N,cut);
    }
  };

  k_init<<<1,64,0,stream>>>(S, SYM);
  k_copy<<<ew(B*H/4),256,0,stream>>>(h0, Hb, B*H/4);

  if(fast){
    // ======================= FAST (MFMA) PATH =======================
    // one-time weight conversion (independent launches, overlap freely)
    cvt(Wpx, WpxT, 512, 512);
    k_packT1<<<(2560*1024+255)/256,256,0,stream>>>(Wenc1,Wpr1,Whh1,WB1T);
    k_packT2<<<(512*1024+255)/256,256,0,stream>>>(Wenc2,Wpr2,WB2T, benc1,bpr1,bhh1,bb1, benc2,bpr2,bb2);
    cvt(Wpz,  WpzT, 256, 512);
    cvt(Wih1, Wih1T,1024,1536);
    cvt(Wpr1, Wpr1T, 512, 512);
    cvt(Wpr2, Wpr2T, 512, 256);
    cvt(Wprn1,Wprn1T,512, 512);
    cvt(Wprn2,Wprn2T,512, 256);
    cvt(Wzn,  WznT,  256, 512);
    cvt(Wga,  WgaT,  768, 512);
    cvt(Woa1, Woa1T, 512, 512);
    cvt(Woa2, Woa2T, 512, 256);
    cvt(Wna1, Wna1T, 512, 512);
    cvt(Wna2, Wna2T, 512, 256);
    cvt(Wen,  WenT,  512, 256);
    cvt(Wact, WactT, 512, 512);
    cvt(Wih2, Wih2T,1024,1536);
    cvt(Whh2, Whh2T, 512,1536);
    cvt(Wcc,  WccT,  512,1000);
    cvt(Wnc,  WncT,  512,1000);

    if(bigphix)
      mf(feat,F,F, 0,0,0, WpxT,512, bpx, 0,0,0, PHIX,H, T*B,H, H);

    // ---- scan ----
    for(int t=0;t<T;t++){
      const float* xp;
      if(bigphix) xp = PHIX + (size_t)t*B*H;
      else { mf(feat+(size_t)t*B*F,F,F, 0,0,0, WpxT,512, bpx, 0,0,0, XP,H, B,H, H); xp = XP; }
      const float* epz = eps_z + (size_t)t*B*Z;
      // C1 = [relu([h|xp]@Wenc1) | relu(h@Wpr1) | h@Whh1]
      mf(Hb,H,H, xp,H,H, WB1T,1024, bb1, 0,0,0, C1,2560, B,2560, 1024);
      // C2 = [enc | pri]
      mf(C1,2560,1024, 0,0,0, WB2T,1024, bb2, 0,0,0, C2,512, B,512, 0);
      k_kldzt<<<128,256,0,stream>>>(C2,512, C2+256,512, epz, ZT, &S[0], B, Z);
      mf(ZT,Z,Z, 0,0,0, WpzT,256, bpz, 0,0,0, ZP,H, B,H, H);
      mf(xp,H,H, ZP,H,H, Wih1T,1024, bih1, 0,0,0, GI,3*H, B,3*H, 0);
      k_gru<<<ew(B*H),256,0,stream>>>(GI,3*H, C1+1024,2560, Hb,B,H);
    }

    // ---- phase 3 (only g = G-1 matters) ----
    mf(Hb,H,H, 0,0,0, Wpr1T,512, bpr1, 0,0,0, P1,H, B,H, H);
    mf(P1,H,H, 0,0,0, Wpr2T,512, bpr2, 0,0,0, OM,Z, B,Z, 0);
    mf(Hb,H,H, 0,0,0, Wprn1T,512, bprn1, 0,0,0, P1,H, B,H, H);
    mf(P1,H,H, 0,0,0, Wprn2T,512, bprn2, 0,0,0, PNH,Z, B,Z, 0);
    k_expand<<<ew(B*Z),256,0,stream>>>(OM, eps_g+(size_t)(G-1)*B*Z, ZT, B*Z, B*Z);
    mf(ZT,Z,Z, 0,0,0, WznT,256, bzn, 0,0,0, E1,H, B,H, H);
    mf(E1,H,H, PNH,Z,Z, WgaT,768, bga, 0,0,0, OA,H, B,H, H);
    mf(PNH,Z,Z, OA,H,H, WgaT,768, bga, 0,0,0, NM,H, B,H, H);
    k_expand<<<ew(A*B*H),256,0,stream>>>(NM, eps_n+(size_t)(G-1)*A*B*H, NACT, B*H, A*B*H);
    mf(NACT,H,H, 0,0,0, Wna1T,512, bna1, 0,0,0, PMID,H, A*B,H, H);
    mf(PMID,H,H, 0,0,0, Wna2T,512, bna2, 0,0,0, PNX,Z, A*B,Z, 0);
    mf(OA,H,H, 0,0,0, Woa1T,512, boa1, 0,0,0, P1,H, B,H, H);
    mf(P1,H,H, 0,0,0, Woa2T,512, boa2, 0,0,0, OAZ,Z, B,Z, 0);
    mf(OAZ,Z,Z, 0,0,0, WenT+256,512, ben, 0,0,0, BASE,Z, B,Z, 0);
    mf(PNX,Z,Z, 0,0,0, WenT,512, 0, BASE,B-1,Z, ENCN,Z, A*B,Z, Z);
    k_sym<<<dim3(32,A),256,0,stream>>>(OM, ENCN, SYM, B*Z);
    k_argmin<<<1,64,0,stream>>>(SYM, A, &JSEL[0], &S[2], 0);
    k_kldsel<<<128,256,0,stream>>>(ENCN, PNX, &JSEL[0], B*Z, &S[1]);
    k_gather<<<ew(B*H),256,0,stream>>>(NACT, &JSEL[0], BUFA, B*H);

    // ---- phase 4 ----
    const float* pre = OA; const float* cur = BUFA;
    float* futbuf[2] = {BUFB, BUFC};
    for(int i=0;i<2;i++){
      mf(pre,H,H, 0,0,0, WactT,512, bact, 0,0,0, PAb,H, B,H, H);
      mf(cur,H,H, 0,0,0, WactT,512, bact, 0,0,0, CAb,H, B,H, H);
      mf(PAb,H,H, CAb,H,H, Wih2T,1024, bih2, 0,0,0, GI,3*H, B,3*H, 0);
      mf(Hb,H,H, 0,0,0, Whh2T,512, bhh2, 0,0,0, GH,3*H, B,3*H, 0);
      k_gru<<<ew(B*H),256,0,stream>>>(GI,3*H, GH,3*H, Hb,B,H);
      pre = cur;
      mf(Hb,H,H, 0,0,0, Wprn1T,512, bprn1, 0,0,0, P1,H, B,H, H);
      mf(P1,H,H, 0,0,0, Wprn2T,512, bprn2, 0,0,0, PNH,Z, B,Z, 0);
      mf(PNH,Z,Z, pre,H,H, WgaT,768, bga, 0,0,0, NM,H, B,H, H);
      k_expand<<<ew(A*B*H),256,0,stream>>>(NM, eps_f+(size_t)i*A*B*H, NACT, B*H, A*B*H);
      mf(NACT,H,H, 0,0,0, Wna1T,512, bna1, 0,0,0, PMID,H, A*B,H, H);
      mf(PMID,H,H, 0,0,0, Wna2T,512, bna2, 0,0,0, PNX,Z, A*B,Z, 0);
      mf(pre,H,H, 0,0,0, Wna1T,512, bna1, 0,0,0, P1,H, B,H, H);
      mf(P1,H,H, 0,0,0, Wna2T,512, bna2, 0,0,0, OAZ,Z, B,Z, 0);
      mf(OAZ,Z,Z, 0,0,0, WenT+256,512, ben, 0,0,0, BASE,Z, B,Z, 0);
      mf(PNX,Z,Z, 0,0,0, WenT,512, 0, BASE,B-1,Z, ENCN,Z, A*B,Z, Z);
      float* symf = (i==0)?SYMF0:SYMF1;
      k_sym<<<dim3(32,A),256,0,stream>>>(OM, ENCN, symf, B*Z);
      k_argmin<<<1,64,0,stream>>>(symf, A, &JSEL[1+i], &S[4], 1);
      k_kldsel<<<128,256,0,stream>>>(ENCN, PNX, &JSEL[1+i], B*Z, &S[3]);
      k_gather<<<ew(B*H),256,0,stream>>>(NACT, &JSEL[1+i], futbuf[i], B*H);
      cur = futbuf[i];
    }
    // ---- outputs ----
    mf(OA,H,H, 0,0,0, WccT,512, bcc, 0,0,0, outCur,C, B,C, 0);
    mf(BUFA,H,H, 0,0,0, WncT,512, bnc, 0,0,0, outFut,C, 3*B,C, 0);
    return;
  }

  // ======================= SAFE (fp32) PATH =======================
  if(bigphix)
    gemm(feat,F,F, 0,0,0, Wpx,H,bpx, 0,0,0, PHIX,H, T*B,H, 1);
  for(int t=0;t<T;t++){
    const float* xp;
    if(bigphix) xp = PHIX + (size_t)t*B*H;
    else { gemm(feat+(size_t)t*B*F,F,F, 0,0,0, Wpx,H,bpx, 0,0,0, XP,H, B,H, 1); xp = XP; }
    const float* epz = eps_z + (size_t)t*B*Z;
    gemm(Hb,H,H, xp,H,H, Wenc1,H,benc1, 0,0,0, E1,H, B,H, 1);
    gemm(E1,H,H, 0,0,0, Wenc2,Z,benc2, 0,0,0, ENC,Z, B,Z, 0);
    gemm(Hb,H,H, 0,0,0, Wpr1,H,bpr1, 0,0,0, P1,H, B,H, 1);
    gemm(P1,H,H, 0,0,0, Wpr2,Z,bpr2, 0,0,0, PRI,Z, B,Z, 0);
    k_kldzt<<<128,256,0,stream>>>(ENC,Z, PRI,Z, epz, ZT, &S[0], B, Z);
    gemm(ZT,Z,Z, 0,0,0, Wpz,H,bpz, 0,0,0, ZP,H, B,H, 1);
    gemm(xp,H,H, ZP,H,H, Wih1,3*H,bih1, 0,0,0, GI,3*H, B,3*H, 0);
    gemm(Hb,H,H, 0,0,0, Whh1,3*H,bhh1, 0,0,0, GH,3*H, B,3*H, 0);
    k_gru<<<ew(B*H),256,0,stream>>>(GI,3*H, GH,3*H, Hb,B,H);
  }
  gemm(Hb,H,H, 0,0,0, Wpr1,H,bpr1, 0,0,0, P1,H, B,H, 1);
  gemm(P1,H,H, 0,0,0, Wpr2,Z,bpr2, 0,0,0, OM,Z, B,Z, 0);
  gemm(Hb,H,H, 0,0,0, Wprn1,H,bprn1, 0,0,0, P1,H, B,H, 1);
  gemm(P1,H,H, 0,0,0, Wprn2,Z,bprn2, 0,0,0, PNH,Z, B,Z, 0);
  k_expand<<<ew(B*Z),256,0,stream>>>(OM, eps_g+(size_t)(G-1)*B*Z, ZT, B*Z, B*Z);
  gemm(ZT,Z,Z, 0,0,0, Wzn,H,bzn, 0,0,0, E1,H, B,H, 1);
  gemm(E1,H,H, PNH,Z,Z, Wga,H,bga, 0,0,0, OA,H, B,H, 1);
  gemm(PNH,Z,Z, OA,H,H, Wga,H,bga, 0,0,0, NM,H, B,H, 1);
  k_expand<<<ew(A*B*H),256,0,stream>>>(NM, eps_n+(size_t)(G-1)*A*B*H, NACT, B*H, A*B*H);
  gemm(NACT,H,H, 0,0,0, Wna1,H,bna1, 0,0,0, PMID,H, A*B,H, 1);
  gemm(PMID,H,H, 0,0,0, Wna2,Z,bna2, 0,0,0, PNX,Z, A*B,Z, 0);
  gemm(OA,H,H, 0,0,0, Woa1,H,boa1, 0,0,0, P1,H, B,H, 1);
  gemm(P1,H,H, 0,0,0, Woa2,Z,boa2, 0,0,0, OAZ,Z, B,Z, 0);
  gemm(OAZ,Z,Z, 0,0,0, Wen+(size_t)Z*Z,Z, ben, 0,0,0, BASE,Z, B,Z, 0);
  gemm(PNX,Z,Z, 0,0,0, Wen,Z, 0, BASE,B-1,Z, ENCN,Z, A*B,Z, 1);
  k_sym<<<dim3(32,A),256,0,stream>>>(OM, ENCN, SYM, B*Z);
  k_argmin<<<1,64,0,stream>>>(SYM, A, &JSEL[0], &S[2], 0);
  k_kldsel<<<128,256,0,stream>>>(ENCN, PNX, &JSEL[0], B*Z, &S[1]);
  k_gather<<<ew(B*H),256,0,stream>>>(NACT, &JSEL[0], BUFA, B*H);
  const float* pre = OA; const float* cur = BUFA;
  float* futbuf[2] = {BUFB, BUFC};
  for(int i=0;i<2;i++){
    gemm(pre,H,H, 0,0,0, Wact,H,bact, 0,0,0, PAb,H, B,H, 1);
    gemm(cur,H,H, 0,0,0, Wact,H,bact, 0,0,0, CAb,H, B,H, 1);
    gemm(PAb,H,H, CAb,H,H, Wih2,3*H,bih2, 0,0,0, GI,3*H, B,3*H, 0);
    gemm(Hb,H,H, 0,0,0, Whh2,3*H,bhh2, 0,0,0, GH,3*H, B,3*H, 0);
    k_gru<<<ew(B*H),256,0,stream>>>(GI,3*H, GH,3*H, Hb,B,H);
    pre = cur;
    gemm(Hb,H,H, 0,0,0, Wprn1,H,bprn1, 0,0,0, P1,H, B,H, 1);
    gemm(P1,H,H, 0,0,0, Wprn2,Z,bprn2, 0,0,0, PNH,Z, B,Z, 0);
    gemm(PNH,Z,Z, pre,H,H, Wga,H,bga, 0,0,0, NM,H, B,H, 1);
    k_expand<<<ew(A*B*H),256,0,stream>>>(NM, eps_f+(size_t)i*A*B*H, NACT, B*H, A*B*H);
    gemm(NACT,H,H, 0,0,0, Wna1,H,bna1, 0,0,0, PMID,H, A*B,H, 1);
    gemm(PMID,H,H, 0,0,0, Wna2,Z,bna2, 0,0,0, PNX,Z, A*B,Z, 0);
    gemm(pre,H,H, 0,0,0, Wna1,H,bna1, 0,0,0, P1,H, B,H, 1);
    gemm(P1,H,H, 0,0,0, Wna2,Z,bna2, 0,0,0, OAZ,Z, B,Z, 0);
    gemm(OAZ,Z,Z, 0,0,0, Wen+(size_t)Z*Z,Z, ben, 0,0,0, BASE,Z, B,Z, 0);
    gemm(PNX,Z,Z, 0,0,0, Wen,Z, 0, BASE,B-1,Z, ENCN,Z, A*B,Z, 1);
    float* symf = (i==0)?SYMF0:SYMF1;
    k_sym<<<dim3(32,A),256,0,stream>>>(OM, ENCN, symf, B*Z);
    k_argmin<<<1,64,0,stream>>>(symf, A, &JSEL[1+i], &S[4], 1);
    k_kldsel<<<128,256,0,stream>>>(ENCN, PNX, &JSEL[1+i], B*Z, &S[3]);
    k_gather<<<ew(B*H),256,0,stream>>>(NACT, &JSEL[1+i], futbuf[i], B*H);
    cur = futbuf[i];
  }
  gemm(OA,H,H, 0,0,0, Wcc,C,bcc, 0,0,0, outCur,C, B,C, 0);
  gemm(BUFA,H,H, 0,0,0, Wnc,C,bnc, 0,0,0, outFut,C, 3*B,C, 0);
}